// Round 4
// baseline (1449.813 us; speedup 1.0000x reference)
//
#include <hip/hip_runtime.h>
#include <hip/hip_bf16.h>

#define V     49152
#define NNZ   442368
#define EPS   1e-5f
#define VOUT  12288
#define SCP   260   // padded LDS row stride for transposed cheb tile (mult of 4 for float4)

// ---------------- row_ptr via binary search + zero stats ----------------
__global__ __launch_bounds__(256) void k_rowptr(const int* __restrict__ rows,
                                                int* __restrict__ rp,
                                                float* __restrict__ stats) {
    int r = blockIdx.x * blockDim.x + threadIdx.x;
    if (r <= V) {
        int lo = 0, hi = NNZ;
        while (lo < hi) {
            int m = (lo + hi) >> 1;
            if (rows[m] < r) lo = m + 1; else hi = m;
        }
        rp[r] = lo;
    }
    if (blockIdx.x == 0 && threadIdx.x < 256) stats[threadIdx.x] = 0.f;
}

// ---------------- X1 = L @ X0 ----------------
__global__ __launch_bounds__(256) void k_spmm1(const float* __restrict__ x,
                                               const int* __restrict__ cols,
                                               const float* __restrict__ vals,
                                               const int* __restrict__ rp,
                                               float* __restrict__ X1) {
    int v = blockIdx.x, t = threadIdx.x;
    int s = rp[v], e = rp[v + 1];
    int i0 = t & 31, b0 = t >> 5;
    float a0 = 0.f, a1 = 0.f;
    for (int n = s; n < e; ++n) {
        int c = cols[n];
        float w = vals[n];
        a0 = fmaf(w, x[(size_t)(b0 * V + c) * 32 + i0], a0);
        a1 = fmaf(w, x[(size_t)((b0 + 8) * V + c) * 32 + i0], a1);
    }
    X1[(size_t)v * 512 + t]       = a0;
    X1[(size_t)v * 512 + t + 256] = a1;
}

// ---------------- X2 = 2 L @ X1 - X0 ----------------
__global__ __launch_bounds__(256) void k_spmm2(const float* __restrict__ x,
                                               const int* __restrict__ cols,
                                               const float* __restrict__ vals,
                                               const int* __restrict__ rp,
                                               const float* __restrict__ X1,
                                               float* __restrict__ X2) {
    int v = blockIdx.x, t = threadIdx.x;
    int s = rp[v], e = rp[v + 1];
    int i0 = t & 31, b0 = t >> 5;
    float a0 = 0.f, a1 = 0.f;
    for (int n = s; n < e; ++n) {
        int c = cols[n];
        float w = vals[n];
        a0 = fmaf(w, X1[(size_t)c * 512 + t], a0);
        a1 = fmaf(w, X1[(size_t)c * 512 + t + 256], a1);
    }
    X2[(size_t)v * 512 + t]       = 2.f * a0 - x[(size_t)(b0 * V + v) * 32 + i0];
    X2[(size_t)v * 512 + t + 256] = 2.f * a1 - x[(size_t)((b0 + 8) * V + v) * 32 + i0];
}

// ---- fused: X3 = 2 L @ X2 - X1 (gathered straight into LDS) + einsum + BN stats + bf16 y ----
__global__ __launch_bounds__(256, 3) void k_cheb_out(const float* __restrict__ x,
                                                     const float* __restrict__ X1,
                                                     const float* __restrict__ X2,
                                                     const float* __restrict__ W,
                                                     const int* __restrict__ cols,
                                                     const float* __restrict__ vals,
                                                     const int* __restrict__ rp,
                                                     unsigned short* __restrict__ Y,
                                                     float* __restrict__ stats) {
    __shared__ float sW[2048];        // 8 KB, W_k as [i][o]
    __shared__ float sC[32 * SCP];    // 33.3 KB, cheb_k transposed: sC[i*SCP + r]
    __shared__ float lsum[64], lsq[64];

    int t = threadIdx.x;
    int v0 = blockIdx.x * 16;
    int i0 = t & 31, b0 = t >> 5;     // channel, batch-octet

    if (t < 64) { lsum[t] = 0.f; lsq[t] = 0.f; }

    int to = t & 7, tr = t >> 3;
    int r0 = tr * 8, o0 = to * 8;
    float acc[8][8];
#pragma unroll
    for (int j = 0; j < 8; ++j)
#pragma unroll
        for (int l = 0; l < 8; ++l) acc[j][l] = 0.f;

    // ---- k=3 first: gather X3 rows for the block's 16 vertices DIRECTLY into sC ----
    for (int j = t; j < 512; j += 256)
        *(float4*)&sW[j * 4] = *(const float4*)&W[3 * 2048 + j * 4];
    for (int vv = 0; vv < 16; ++vv) {
        int v = v0 + vv;
        int s = rp[v], e = rp[v + 1];
        float a0 = 0.f, a1 = 0.f;
        for (int n = s; n < e; ++n) {
            int c = cols[n];
            float w = vals[n];
            a0 = fmaf(w, X2[(size_t)c * 512 + t], a0);
            a1 = fmaf(w, X2[(size_t)c * 512 + t + 256], a1);
        }
        sC[i0 * SCP + vv * 16 + b0]     = 2.f * a0 - X1[(size_t)v * 512 + t];
        sC[i0 * SCP + vv * 16 + b0 + 8] = 2.f * a1 - X1[(size_t)v * 512 + t + 256];
    }
    __syncthreads();
#pragma unroll
    for (int i = 0; i < 32; ++i) {
        float4 ca = *(const float4*)&sC[i * SCP + r0];
        float4 cb = *(const float4*)&sC[i * SCP + r0 + 4];
        float4 wa = *(const float4*)&sW[i * 64 + o0];
        float4 wb = *(const float4*)&sW[i * 64 + o0 + 4];
        float c[8] = {ca.x, ca.y, ca.z, ca.w, cb.x, cb.y, cb.z, cb.w};
        float w[8] = {wa.x, wa.y, wa.z, wa.w, wb.x, wb.y, wb.z, wb.w};
#pragma unroll
        for (int j = 0; j < 8; ++j)
#pragma unroll
            for (int l = 0; l < 8; ++l)
                acc[j][l] = fmaf(c[j], w[l], acc[j][l]);
    }

    // ---- k = 0,1,2 ----
    for (int k = 0; k < 3; ++k) {
        __syncthreads();
        for (int j = t; j < 512; j += 256)
            *(float4*)&sW[j * 4] = *(const float4*)&W[k * 2048 + j * 4];
        for (int j = t; j < 2048; j += 256) {
            int r = j >> 3, i4 = j & 7;
            int vv = r >> 4, b = r & 15;
            int v = v0 + vv;
            float4 val;
            if (k == 0)      val = *(const float4*)&x[(size_t)(b * V + v) * 32 + i4 * 4];
            else if (k == 1) val = *(const float4*)&X1[(size_t)v * 512 + b * 32 + i4 * 4];
            else             val = *(const float4*)&X2[(size_t)v * 512 + b * 32 + i4 * 4];
            int ib = i4 * 4;
            sC[(ib + 0) * SCP + r] = val.x;
            sC[(ib + 1) * SCP + r] = val.y;
            sC[(ib + 2) * SCP + r] = val.z;
            sC[(ib + 3) * SCP + r] = val.w;
        }
        __syncthreads();
#pragma unroll
        for (int i = 0; i < 32; ++i) {
            float4 ca = *(const float4*)&sC[i * SCP + r0];
            float4 cb = *(const float4*)&sC[i * SCP + r0 + 4];
            float4 wa = *(const float4*)&sW[i * 64 + o0];
            float4 wb = *(const float4*)&sW[i * 64 + o0 + 4];
            float c[8] = {ca.x, ca.y, ca.z, ca.w, cb.x, cb.y, cb.z, cb.w};
            float w[8] = {wa.x, wa.y, wa.z, wa.w, wb.x, wb.y, wb.z, wb.w};
#pragma unroll
            for (int j = 0; j < 8; ++j)
#pragma unroll
                for (int l = 0; l < 8; ++l)
                    acc[j][l] = fmaf(c[j], w[l], acc[j][l]);
        }
    }

    // y write (bf16) — layout Y[v][b][o]
#pragma unroll
    for (int j = 0; j < 8; ++j) {
        int r = r0 + j;
        int vv = r >> 4, b = r & 15;
        union { unsigned short u[8]; uint4 q; } p;
#pragma unroll
        for (int l = 0; l < 8; ++l) {
            __hip_bfloat16 h = __float2bfloat16(acc[j][l]);
            p.u[l] = *reinterpret_cast<unsigned short*>(&h);
        }
        *(uint4*)&Y[(size_t)(v0 + vv) * 1024 + b * 64 + o0] = p.q;
    }

    // BN partial sums (exact fp32 accumulators)
#pragma unroll
    for (int l = 0; l < 8; ++l) {
        float s = 0.f, q = 0.f;
#pragma unroll
        for (int j = 0; j < 8; ++j) { float a = acc[j][l]; s += a; q = fmaf(a, a, q); }
        atomicAdd(&lsum[o0 + l], s);
        atomicAdd(&lsq[o0 + l], q);
    }
    __syncthreads();
    if (t < 64) {
        atomicAdd(&stats[t], lsum[t]);
        atomicAdd(&stats[64 + t], lsq[t]);
    }
}

// ---------------- finalize BN scale/shift ----------------
__global__ void k_bnfin(const float* __restrict__ gamma, const float* __restrict__ beta,
                        float* __restrict__ stats) {
    int o = threadIdx.x;
    if (o < 64) {
        float n = (float)(16 * V);
        float mean = stats[o] / n;
        float var = stats[64 + o] / n - mean * mean;
        float sc = gamma[o] * rsqrtf(var + EPS);
        stats[128 + o] = sc;
        stats[192 + o] = beta[o] - mean * sc;
    }
}

// ---------------- BN apply + ReLU + pool(4), bf16 y in ----------------
__global__ __launch_bounds__(256) void k_pool(const unsigned short* __restrict__ Y,
                                              const float* __restrict__ stats,
                                              float* __restrict__ out) {
    int id = blockIdx.x * blockDim.x + threadIdx.x;
    int o4 = id & 15;
    int b  = (id >> 4) & 15;
    int vp = id >> 8;
    float4 sc = *(const float4*)&stats[128 + o4 * 4];
    float4 sh = *(const float4*)&stats[192 + o4 * 4];
    float ax = 0.f, ay = 0.f, az = 0.f, aw = 0.f;
#pragma unroll
    for (int j = 0; j < 4; ++j) {
        ushort4 u = *(const ushort4*)&Y[(size_t)((vp * 4 + j) * 16 + b) * 64 + o4 * 4];
        float tx = __uint_as_float((unsigned)u.x << 16);
        float ty = __uint_as_float((unsigned)u.y << 16);
        float tz = __uint_as_float((unsigned)u.z << 16);
        float tw = __uint_as_float((unsigned)u.w << 16);
        ax += fmaxf(fmaf(tx, sc.x, sh.x), 0.f);
        ay += fmaxf(fmaf(ty, sc.y, sh.y), 0.f);
        az += fmaxf(fmaf(tz, sc.z, sh.z), 0.f);
        aw += fmaxf(fmaf(tw, sc.w, sh.w), 0.f);
    }
    float4 res = {ax * 0.25f, ay * 0.25f, az * 0.25f, aw * 0.25f};
    *(float4*)&out[(size_t)((b * VOUT + vp) * 16 + o4) * 4] = res;
}

extern "C" void kernel_launch(void* const* d_in, const int* in_sizes, int n_in,
                              void* d_out, int out_size, void* d_ws, size_t ws_size,
                              hipStream_t stream) {
    const float* x     = (const float*)d_in[0];
    const float* vals  = (const float*)d_in[1];
    const float* W     = (const float*)d_in[2];
    const float* gamma = (const float*)d_in[3];
    const float* beta  = (const float*)d_in[4];
    const int*   rows  = (const int*)d_in[5];
    const int*   cols  = (const int*)d_in[6];
    float* out = (float*)d_out;

    char* ws = (char*)d_ws;
    float* X1 = (float*)ws;                                  // 100,663,296 B
    float* X2 = (float*)(ws + 100663296UL);                  // 100,663,296 B
    unsigned short* Y = (unsigned short*)(ws + 201326592UL); // 100,663,296 B (bf16 [v][b][o])
    int*   rp    = (int*)(ws + 301989888UL);                 // 196,612 B
    float* stats = (float*)(ws + 301989888UL + 197120UL);    // 1 KB

    k_rowptr<<<193, 256, 0, stream>>>(rows, rp, stats);
    k_spmm1<<<V, 256, 0, stream>>>(x, cols, vals, rp, X1);
    k_spmm2<<<V, 256, 0, stream>>>(x, cols, vals, rp, X1, X2);
    k_cheb_out<<<V / 16, 256, 0, stream>>>(x, X1, X2, W, cols, vals, rp, Y, stats);
    k_bnfin<<<1, 64, 0, stream>>>(gamma, beta, stats);
    k_pool<<<12288, 256, 0, stream>>>(Y, stats, out);
}

// Round 5
// 825.066 us; speedup vs baseline: 1.7572x; 1.7572x over previous
//
#include <hip/hip_runtime.h>
#include <hip/hip_bf16.h>

#define V     49152
#define NNZ   442368
#define EPS   1e-5f
#define VOUT  12288
#define SCW   132   // padded LDS row stride (mult of 4 for float4), 128 rows + 4 pad

// ---------------- row_ptr via binary search + zero stats ----------------
__global__ __launch_bounds__(256) void k_rowptr(const int* __restrict__ rows,
                                                int* __restrict__ rp,
                                                float* __restrict__ stats) {
    int r = blockIdx.x * blockDim.x + threadIdx.x;
    if (r <= V) {
        int lo = 0, hi = NNZ;
        while (lo < hi) {
            int m = (lo + hi) >> 1;
            if (rows[m] < r) lo = m + 1; else hi = m;
        }
        rp[r] = lo;
    }
    if (blockIdx.x == 0 && threadIdx.x < 256) stats[threadIdx.x] = 0.f;
}

// ---------------- X1 = L @ X0 ----------------
__global__ __launch_bounds__(256) void k_spmm1(const float* __restrict__ x,
                                               const int* __restrict__ cols,
                                               const float* __restrict__ vals,
                                               const int* __restrict__ rp,
                                               float* __restrict__ X1) {
    int v = blockIdx.x, t = threadIdx.x;
    int s = rp[v], e = rp[v + 1];
    int i0 = t & 31, b0 = t >> 5;
    float a0 = 0.f, a1 = 0.f;
    for (int n = s; n < e; ++n) {
        int c = cols[n];
        float w = vals[n];
        a0 = fmaf(w, x[(size_t)(b0 * V + c) * 32 + i0], a0);
        a1 = fmaf(w, x[(size_t)((b0 + 8) * V + c) * 32 + i0], a1);
    }
    X1[(size_t)v * 512 + t]       = a0;
    X1[(size_t)v * 512 + t + 256] = a1;
}

// ---------------- X2 = 2 L @ X1 - X0 ----------------
__global__ __launch_bounds__(256) void k_spmm2(const float* __restrict__ x,
                                               const int* __restrict__ cols,
                                               const float* __restrict__ vals,
                                               const int* __restrict__ rp,
                                               const float* __restrict__ X1,
                                               float* __restrict__ X2) {
    int v = blockIdx.x, t = threadIdx.x;
    int s = rp[v], e = rp[v + 1];
    int i0 = t & 31, b0 = t >> 5;
    float a0 = 0.f, a1 = 0.f;
    for (int n = s; n < e; ++n) {
        int c = cols[n];
        float w = vals[n];
        a0 = fmaf(w, X1[(size_t)c * 512 + t], a0);
        a1 = fmaf(w, X1[(size_t)c * 512 + t + 256], a1);
    }
    X2[(size_t)v * 512 + t]       = 2.f * a0 - x[(size_t)(b0 * V + v) * 32 + i0];
    X2[(size_t)v * 512 + t + 256] = 2.f * a1 - x[(size_t)((b0 + 8) * V + v) * 32 + i0];
}

// ---- fused: X3 = 2 L @ X2 - X1 (gathered straight into LDS) + einsum + BN stats + bf16 y ----
// 8 vertices per block (128 rows x 64 cols), 256 threads, acc[4][8] per thread.
__global__ __launch_bounds__(256) void k_cheb_out(const float* __restrict__ x,
                                                  const float* __restrict__ X1,
                                                  const float* __restrict__ X2,
                                                  const float* __restrict__ W,
                                                  const int* __restrict__ cols,
                                                  const float* __restrict__ vals,
                                                  const int* __restrict__ rp,
                                                  unsigned short* __restrict__ Y,
                                                  float* __restrict__ stats) {
    __shared__ float sW[2048];        // 8 KB, W_k as [i][o]
    __shared__ float sC[32 * SCW];    // 16.9 KB, cheb_k transposed: sC[i*SCW + r], r = vv*16+b
    __shared__ float lsum[64], lsq[64];

    int t = threadIdx.x;
    int v0 = blockIdx.x * 8;
    int i0 = t & 31, b0 = t >> 5;     // channel, batch-octet (0..7)

    if (t < 64) { lsum[t] = 0.f; lsq[t] = 0.f; }

    int to = t & 7, tr = t >> 3;      // col-group (8 cols), row-group (4 rows)
    int r0 = tr * 4, o0 = to * 8;
    float acc[4][8];
#pragma unroll
    for (int j = 0; j < 4; ++j)
#pragma unroll
        for (int l = 0; l < 8; ++l) acc[j][l] = 0.f;

    // ---- k=3 first: gather X3 rows for the block's 8 vertices DIRECTLY into sC ----
    for (int j = t; j < 512; j += 256)
        *(float4*)&sW[j * 4] = *(const float4*)&W[3 * 2048 + j * 4];
    for (int vv = 0; vv < 8; ++vv) {
        int v = v0 + vv;
        int s = rp[v], e = rp[v + 1];
        float a0 = 0.f, a1 = 0.f;
        for (int n = s; n < e; ++n) {
            int c = cols[n];
            float w = vals[n];
            a0 = fmaf(w, X2[(size_t)c * 512 + t], a0);
            a1 = fmaf(w, X2[(size_t)c * 512 + t + 256], a1);
        }
        sC[i0 * SCW + vv * 16 + b0]     = 2.f * a0 - X1[(size_t)v * 512 + t];
        sC[i0 * SCW + vv * 16 + b0 + 8] = 2.f * a1 - X1[(size_t)v * 512 + t + 256];
    }
    __syncthreads();
#pragma unroll
    for (int i = 0; i < 32; ++i) {
        float4 ca = *(const float4*)&sC[i * SCW + r0];
        float4 wa = *(const float4*)&sW[i * 64 + o0];
        float4 wb = *(const float4*)&sW[i * 64 + o0 + 4];
        float c[4] = {ca.x, ca.y, ca.z, ca.w};
        float w[8] = {wa.x, wa.y, wa.z, wa.w, wb.x, wb.y, wb.z, wb.w};
#pragma unroll
        for (int j = 0; j < 4; ++j)
#pragma unroll
            for (int l = 0; l < 8; ++l)
                acc[j][l] = fmaf(c[j], w[l], acc[j][l]);
    }

    // ---- k = 0,1,2 ----
    for (int k = 0; k < 3; ++k) {
        __syncthreads();
        for (int j = t; j < 512; j += 256)
            *(float4*)&sW[j * 4] = *(const float4*)&W[k * 2048 + j * 4];
        for (int j = t; j < 1024; j += 256) {
            int r = j >> 3, i4 = j & 7;   // r in [0,128): vv = r>>4, b = r&15
            int vv = r >> 4, b = r & 15;
            int v = v0 + vv;
            float4 val;
            if (k == 0)      val = *(const float4*)&x[(size_t)(b * V + v) * 32 + i4 * 4];
            else if (k == 1) val = *(const float4*)&X1[(size_t)v * 512 + b * 32 + i4 * 4];
            else             val = *(const float4*)&X2[(size_t)v * 512 + b * 32 + i4 * 4];
            int ib = i4 * 4;
            sC[(ib + 0) * SCW + r] = val.x;
            sC[(ib + 1) * SCW + r] = val.y;
            sC[(ib + 2) * SCW + r] = val.z;
            sC[(ib + 3) * SCW + r] = val.w;
        }
        __syncthreads();
#pragma unroll
        for (int i = 0; i < 32; ++i) {
            float4 ca = *(const float4*)&sC[i * SCW + r0];
            float4 wa = *(const float4*)&sW[i * 64 + o0];
            float4 wb = *(const float4*)&sW[i * 64 + o0 + 4];
            float c[4] = {ca.x, ca.y, ca.z, ca.w};
            float w[8] = {wa.x, wa.y, wa.z, wa.w, wb.x, wb.y, wb.z, wb.w};
#pragma unroll
            for (int j = 0; j < 4; ++j)
#pragma unroll
                for (int l = 0; l < 8; ++l)
                    acc[j][l] = fmaf(c[j], w[l], acc[j][l]);
        }
    }

    // y write (bf16) — layout Y[v][b][o]
#pragma unroll
    for (int j = 0; j < 4; ++j) {
        int r = r0 + j;
        int vv = r >> 4, b = r & 15;
        union { unsigned short u[8]; uint4 q; } p;
#pragma unroll
        for (int l = 0; l < 8; ++l) {
            __hip_bfloat16 h = __float2bfloat16(acc[j][l]);
            p.u[l] = *reinterpret_cast<unsigned short*>(&h);
        }
        *(uint4*)&Y[(size_t)(v0 + vv) * 1024 + b * 64 + o0] = p.q;
    }

    // BN partial sums (exact fp32 accumulators)
#pragma unroll
    for (int l = 0; l < 8; ++l) {
        float s = 0.f, q = 0.f;
#pragma unroll
        for (int j = 0; j < 4; ++j) { float a = acc[j][l]; s += a; q = fmaf(a, a, q); }
        atomicAdd(&lsum[o0 + l], s);
        atomicAdd(&lsq[o0 + l], q);
    }
    __syncthreads();
    if (t < 64) {
        atomicAdd(&stats[t], lsum[t]);
        atomicAdd(&stats[64 + t], lsq[t]);
    }
}

// ---------------- finalize BN scale/shift ----------------
__global__ void k_bnfin(const float* __restrict__ gamma, const float* __restrict__ beta,
                        float* __restrict__ stats) {
    int o = threadIdx.x;
    if (o < 64) {
        float n = (float)(16 * V);
        float mean = stats[o] / n;
        float var = stats[64 + o] / n - mean * mean;
        float sc = gamma[o] * rsqrtf(var + EPS);
        stats[128 + o] = sc;
        stats[192 + o] = beta[o] - mean * sc;
    }
}

// ---------------- BN apply + ReLU + pool(4), bf16 y in ----------------
__global__ __launch_bounds__(256) void k_pool(const unsigned short* __restrict__ Y,
                                              const float* __restrict__ stats,
                                              float* __restrict__ out) {
    int id = blockIdx.x * blockDim.x + threadIdx.x;
    int o4 = id & 15;
    int b  = (id >> 4) & 15;
    int vp = id >> 8;
    float4 sc = *(const float4*)&stats[128 + o4 * 4];
    float4 sh = *(const float4*)&stats[192 + o4 * 4];
    float ax = 0.f, ay = 0.f, az = 0.f, aw = 0.f;
#pragma unroll
    for (int j = 0; j < 4; ++j) {
        ushort4 u = *(const ushort4*)&Y[(size_t)((vp * 4 + j) * 16 + b) * 64 + o4 * 4];
        float tx = __uint_as_float((unsigned)u.x << 16);
        float ty = __uint_as_float((unsigned)u.y << 16);
        float tz = __uint_as_float((unsigned)u.z << 16);
        float tw = __uint_as_float((unsigned)u.w << 16);
        ax += fmaxf(fmaf(tx, sc.x, sh.x), 0.f);
        ay += fmaxf(fmaf(ty, sc.y, sh.y), 0.f);
        az += fmaxf(fmaf(tz, sc.z, sh.z), 0.f);
        aw += fmaxf(fmaf(tw, sc.w, sh.w), 0.f);
    }
    float4 res = {ax * 0.25f, ay * 0.25f, az * 0.25f, aw * 0.25f};
    *(float4*)&out[(size_t)((b * VOUT + vp) * 16 + o4) * 4] = res;
}

extern "C" void kernel_launch(void* const* d_in, const int* in_sizes, int n_in,
                              void* d_out, int out_size, void* d_ws, size_t ws_size,
                              hipStream_t stream) {
    const float* x     = (const float*)d_in[0];
    const float* vals  = (const float*)d_in[1];
    const float* W     = (const float*)d_in[2];
    const float* gamma = (const float*)d_in[3];
    const float* beta  = (const float*)d_in[4];
    const int*   rows  = (const int*)d_in[5];
    const int*   cols  = (const int*)d_in[6];
    float* out = (float*)d_out;

    char* ws = (char*)d_ws;
    float* X1 = (float*)ws;                                  // 100,663,296 B
    float* X2 = (float*)(ws + 100663296UL);                  // 100,663,296 B
    unsigned short* Y = (unsigned short*)(ws + 201326592UL); // 100,663,296 B (bf16 [v][b][o])
    int*   rp    = (int*)(ws + 301989888UL);                 // 196,612 B
    float* stats = (float*)(ws + 301989888UL + 197120UL);    // 1 KB

    k_rowptr<<<193, 256, 0, stream>>>(rows, rp, stats);
    k_spmm1<<<V, 256, 0, stream>>>(x, cols, vals, rp, X1);
    k_spmm2<<<V, 256, 0, stream>>>(x, cols, vals, rp, X1, X2);
    k_cheb_out<<<V / 8, 256, 0, stream>>>(x, X1, X2, W, cols, vals, rp, Y, stats);
    k_bnfin<<<1, 64, 0, stream>>>(gamma, beta, stats);
    k_pool<<<12288, 256, 0, stream>>>(Y, stats, out);
}

// Round 6
// 675.313 us; speedup vs baseline: 2.1469x; 1.2218x over previous
//
#include <hip/hip_runtime.h>
#include <hip/hip_bf16.h>

#define V     49152
#define NNZ   442368
#define EPS   1e-5f
#define VOUT  12288
#define SCW   132   // padded LDS row stride (mult of 4 for float4)

// ---------------- row_ptr via binary search + zero stats ----------------
__global__ __launch_bounds__(256) void k_rowptr(const int* __restrict__ rows,
                                                int* __restrict__ rp,
                                                float* __restrict__ stats) {
    int r = blockIdx.x * blockDim.x + threadIdx.x;
    if (r <= V) {
        int lo = 0, hi = NNZ;
        while (lo < hi) {
            int m = (lo + hi) >> 1;
            if (rows[m] < r) lo = m + 1; else hi = m;
        }
        rp[r] = lo;
    }
    if (blockIdx.x == 0 && threadIdx.x < 256) stats[threadIdx.x] = 0.f;
}

// ---------------- X1 = L @ X0 : one wave per vertex, 4 vertices/block ----------------
__global__ __launch_bounds__(256) void k_spmm1(const float* __restrict__ x,
                                               const int* __restrict__ cols,
                                               const float* __restrict__ vals,
                                               const int* __restrict__ rp,
                                               float* __restrict__ X1) {
    int t = threadIdx.x;
    int wave = t >> 6, lane = t & 63;
    int v = blockIdx.x * 4 + wave;
    int f0 = lane * 8;
    int b = f0 >> 5, i = f0 & 31;           // 8 features lie within one b
    int s = rp[v], e = rp[v + 1];
    float4 A = {0.f, 0.f, 0.f, 0.f}, Bq = {0.f, 0.f, 0.f, 0.f};
    for (int n = s; n < e; ++n) {
        int c = cols[n];
        float w = vals[n];
        const float4* p = (const float4*)&x[(size_t)(b * V + c) * 32 + i];
        float4 q0 = p[0], q1 = p[1];
        A.x = fmaf(w, q0.x, A.x); A.y = fmaf(w, q0.y, A.y);
        A.z = fmaf(w, q0.z, A.z); A.w = fmaf(w, q0.w, A.w);
        Bq.x = fmaf(w, q1.x, Bq.x); Bq.y = fmaf(w, q1.y, Bq.y);
        Bq.z = fmaf(w, q1.z, Bq.z); Bq.w = fmaf(w, q1.w, Bq.w);
    }
    float4* o = (float4*)&X1[(size_t)v * 512 + f0];
    o[0] = A; o[1] = Bq;
}

// ---------------- X2 = 2 L @ X1 - X0 : one wave per vertex ----------------
__global__ __launch_bounds__(256) void k_spmm2(const float* __restrict__ x,
                                               const int* __restrict__ cols,
                                               const float* __restrict__ vals,
                                               const int* __restrict__ rp,
                                               const float* __restrict__ X1,
                                               float* __restrict__ X2) {
    int t = threadIdx.x;
    int wave = t >> 6, lane = t & 63;
    int v = blockIdx.x * 4 + wave;
    int f0 = lane * 8;
    int b = f0 >> 5, i = f0 & 31;
    int s = rp[v], e = rp[v + 1];
    float4 A = {0.f, 0.f, 0.f, 0.f}, Bq = {0.f, 0.f, 0.f, 0.f};
    for (int n = s; n < e; ++n) {
        int c = cols[n];
        float w = vals[n];
        const float4* p = (const float4*)&X1[(size_t)c * 512 + f0];
        float4 q0 = p[0], q1 = p[1];
        A.x = fmaf(w, q0.x, A.x); A.y = fmaf(w, q0.y, A.y);
        A.z = fmaf(w, q0.z, A.z); A.w = fmaf(w, q0.w, A.w);
        Bq.x = fmaf(w, q1.x, Bq.x); Bq.y = fmaf(w, q1.y, Bq.y);
        Bq.z = fmaf(w, q1.z, Bq.z); Bq.w = fmaf(w, q1.w, Bq.w);
    }
    const float4* px = (const float4*)&x[(size_t)(b * V + v) * 32 + i];
    float4 x0 = px[0], x1 = px[1];
    float4 r0 = {2.f * A.x - x0.x, 2.f * A.y - x0.y, 2.f * A.z - x0.z, 2.f * A.w - x0.w};
    float4 r1 = {2.f * Bq.x - x1.x, 2.f * Bq.y - x1.y, 2.f * Bq.z - x1.z, 2.f * Bq.w - x1.w};
    float4* o = (float4*)&X2[(size_t)v * 512 + f0];
    o[0] = r0; o[1] = r1;
}

// ---- fused: X3 = 2 L @ X2 - X1 (wave-parallel gather into LDS) + einsum + BN + bf16 y ----
// 8 vertices per block, 256 threads; gather: wave w handles vertices 2w, 2w+1.
__global__ __launch_bounds__(256) void k_cheb_out(const float* __restrict__ x,
                                                  const float* __restrict__ X1,
                                                  const float* __restrict__ X2,
                                                  const float* __restrict__ W,
                                                  const int* __restrict__ cols,
                                                  const float* __restrict__ vals,
                                                  const int* __restrict__ rp,
                                                  unsigned short* __restrict__ Y,
                                                  float* __restrict__ stats) {
    __shared__ float sW[2048];        // 8 KB, W_k as [i][o]
    __shared__ float sC[32 * SCW];    // 16.9 KB, cheb_k transposed: sC[i*SCW + r], r = vv*16+b
    __shared__ float lsum[64], lsq[64];

    int t = threadIdx.x;
    int v0 = blockIdx.x * 8;
    int wave = t >> 6, lane = t & 63;

    if (t < 64) { lsum[t] = 0.f; lsq[t] = 0.f; }

    int to = t & 7, tr = t >> 3;
    int r0 = tr * 4, o0 = to * 8;
    float acc[4][8];
#pragma unroll
    for (int j = 0; j < 4; ++j)
#pragma unroll
        for (int l = 0; l < 8; ++l) acc[j][l] = 0.f;

    // ---- k=3 first: wave-parallel gather of X3 rows straight into sC ----
    for (int j = t; j < 512; j += 256)
        *(float4*)&sW[j * 4] = *(const float4*)&W[3 * 2048 + j * 4];
    {
        int f0 = lane * 8;
#pragma unroll
        for (int u = 0; u < 2; ++u) {
            int vv = wave * 2 + u;
            int v = v0 + vv;
            int s = rp[v], e = rp[v + 1];
            float4 A = {0.f, 0.f, 0.f, 0.f}, Bq = {0.f, 0.f, 0.f, 0.f};
            for (int n = s; n < e; ++n) {
                int c = cols[n];
                float w = vals[n];
                const float4* p = (const float4*)&X2[(size_t)c * 512 + f0];
                float4 q0 = p[0], q1 = p[1];
                A.x = fmaf(w, q0.x, A.x); A.y = fmaf(w, q0.y, A.y);
                A.z = fmaf(w, q0.z, A.z); A.w = fmaf(w, q0.w, A.w);
                Bq.x = fmaf(w, q1.x, Bq.x); Bq.y = fmaf(w, q1.y, Bq.y);
                Bq.z = fmaf(w, q1.z, Bq.z); Bq.w = fmaf(w, q1.w, Bq.w);
            }
            const float4* p1 = (const float4*)&X1[(size_t)v * 512 + f0];
            float4 s0 = p1[0], s1 = p1[1];
            float r[8] = {2.f * A.x - s0.x, 2.f * A.y - s0.y, 2.f * A.z - s0.z, 2.f * A.w - s0.w,
                          2.f * Bq.x - s1.x, 2.f * Bq.y - s1.y, 2.f * Bq.z - s1.z, 2.f * Bq.w - s1.w};
#pragma unroll
            for (int j = 0; j < 8; ++j) {
                int f = f0 + j;
                sC[(f & 31) * SCW + vv * 16 + (f >> 5)] = r[j];
            }
        }
    }
    __syncthreads();
#pragma unroll
    for (int i = 0; i < 32; ++i) {
        float4 ca = *(const float4*)&sC[i * SCW + r0];
        float4 wa = *(const float4*)&sW[i * 64 + o0];
        float4 wb = *(const float4*)&sW[i * 64 + o0 + 4];
        float c[4] = {ca.x, ca.y, ca.z, ca.w};
        float w[8] = {wa.x, wa.y, wa.z, wa.w, wb.x, wb.y, wb.z, wb.w};
#pragma unroll
        for (int j = 0; j < 4; ++j)
#pragma unroll
            for (int l = 0; l < 8; ++l)
                acc[j][l] = fmaf(c[j], w[l], acc[j][l]);
    }

    // ---- k = 0,1,2 ----
    for (int k = 0; k < 3; ++k) {
        __syncthreads();
        for (int j = t; j < 512; j += 256)
            *(float4*)&sW[j * 4] = *(const float4*)&W[k * 2048 + j * 4];
        for (int j = t; j < 1024; j += 256) {
            int r = j >> 3, i4 = j & 7;
            int vv = r >> 4, b = r & 15;
            int v = v0 + vv;
            float4 val;
            if (k == 0)      val = *(const float4*)&x[(size_t)(b * V + v) * 32 + i4 * 4];
            else if (k == 1) val = *(const float4*)&X1[(size_t)v * 512 + b * 32 + i4 * 4];
            else             val = *(const float4*)&X2[(size_t)v * 512 + b * 32 + i4 * 4];
            int ib = i4 * 4;
            sC[(ib + 0) * SCW + r] = val.x;
            sC[(ib + 1) * SCW + r] = val.y;
            sC[(ib + 2) * SCW + r] = val.z;
            sC[(ib + 3) * SCW + r] = val.w;
        }
        __syncthreads();
#pragma unroll
        for (int i = 0; i < 32; ++i) {
            float4 ca = *(const float4*)&sC[i * SCW + r0];
            float4 wa = *(const float4*)&sW[i * 64 + o0];
            float4 wb = *(const float4*)&sW[i * 64 + o0 + 4];
            float c[4] = {ca.x, ca.y, ca.z, ca.w};
            float w[8] = {wa.x, wa.y, wa.z, wa.w, wb.x, wb.y, wb.z, wb.w};
#pragma unroll
            for (int j = 0; j < 4; ++j)
#pragma unroll
                for (int l = 0; l < 8; ++l)
                    acc[j][l] = fmaf(c[j], w[l], acc[j][l]);
        }
    }

    // y write (bf16) — layout Y[v][b][o]
#pragma unroll
    for (int j = 0; j < 4; ++j) {
        int r = r0 + j;
        int vv = r >> 4, b = r & 15;
        union { unsigned short u[8]; uint4 q; } p;
#pragma unroll
        for (int l = 0; l < 8; ++l) {
            __hip_bfloat16 h = __float2bfloat16(acc[j][l]);
            p.u[l] = *reinterpret_cast<unsigned short*>(&h);
        }
        *(uint4*)&Y[(size_t)(v0 + vv) * 1024 + b * 64 + o0] = p.q;
    }

    // BN partial sums (exact fp32 accumulators)
#pragma unroll
    for (int l = 0; l < 8; ++l) {
        float s = 0.f, q = 0.f;
#pragma unroll
        for (int j = 0; j < 4; ++j) { float a = acc[j][l]; s += a; q = fmaf(a, a, q); }
        atomicAdd(&lsum[o0 + l], s);
        atomicAdd(&lsq[o0 + l], q);
    }
    __syncthreads();
    if (t < 64) {
        atomicAdd(&stats[t], lsum[t]);
        atomicAdd(&stats[64 + t], lsq[t]);
    }
}

// ---------------- finalize BN scale/shift ----------------
__global__ void k_bnfin(const float* __restrict__ gamma, const float* __restrict__ beta,
                        float* __restrict__ stats) {
    int o = threadIdx.x;
    if (o < 64) {
        float n = (float)(16 * V);
        float mean = stats[o] / n;
        float var = stats[64 + o] / n - mean * mean;
        float sc = gamma[o] * rsqrtf(var + EPS);
        stats[128 + o] = sc;
        stats[192 + o] = beta[o] - mean * sc;
    }
}

// ---------------- BN apply + ReLU + pool(4), bf16 y in ----------------
__global__ __launch_bounds__(256) void k_pool(const unsigned short* __restrict__ Y,
                                              const float* __restrict__ stats,
                                              float* __restrict__ out) {
    int id = blockIdx.x * blockDim.x + threadIdx.x;
    int o4 = id & 15;
    int b  = (id >> 4) & 15;
    int vp = id >> 8;
    float4 sc = *(const float4*)&stats[128 + o4 * 4];
    float4 sh = *(const float4*)&stats[192 + o4 * 4];
    float ax = 0.f, ay = 0.f, az = 0.f, aw = 0.f;
#pragma unroll
    for (int j = 0; j < 4; ++j) {
        ushort4 u = *(const ushort4*)&Y[(size_t)((vp * 4 + j) * 16 + b) * 64 + o4 * 4];
        float tx = __uint_as_float((unsigned)u.x << 16);
        float ty = __uint_as_float((unsigned)u.y << 16);
        float tz = __uint_as_float((unsigned)u.z << 16);
        float tw = __uint_as_float((unsigned)u.w << 16);
        ax += fmaxf(fmaf(tx, sc.x, sh.x), 0.f);
        ay += fmaxf(fmaf(ty, sc.y, sh.y), 0.f);
        az += fmaxf(fmaf(tz, sc.z, sh.z), 0.f);
        aw += fmaxf(fmaf(tw, sc.w, sh.w), 0.f);
    }
    float4 res = {ax * 0.25f, ay * 0.25f, az * 0.25f, aw * 0.25f};
    *(float4*)&out[(size_t)((b * VOUT + vp) * 16 + o4) * 4] = res;
}

extern "C" void kernel_launch(void* const* d_in, const int* in_sizes, int n_in,
                              void* d_out, int out_size, void* d_ws, size_t ws_size,
                              hipStream_t stream) {
    const float* x     = (const float*)d_in[0];
    const float* vals  = (const float*)d_in[1];
    const float* W     = (const float*)d_in[2];
    const float* gamma = (const float*)d_in[3];
    const float* beta  = (const float*)d_in[4];
    const int*   rows  = (const int*)d_in[5];
    const int*   cols  = (const int*)d_in[6];
    float* out = (float*)d_out;

    char* ws = (char*)d_ws;
    float* X1 = (float*)ws;                                  // 100,663,296 B
    float* X2 = (float*)(ws + 100663296UL);                  // 100,663,296 B
    unsigned short* Y = (unsigned short*)(ws + 201326592UL); // 100,663,296 B (bf16 [v][b][o])
    int*   rp    = (int*)(ws + 301989888UL);                 // 196,612 B
    float* stats = (float*)(ws + 301989888UL + 197120UL);    // 1 KB

    k_rowptr<<<193, 256, 0, stream>>>(rows, rp, stats);
    k_spmm1<<<V / 4, 256, 0, stream>>>(x, cols, vals, rp, X1);
    k_spmm2<<<V / 4, 256, 0, stream>>>(x, cols, vals, rp, X1, X2);
    k_cheb_out<<<V / 8, 256, 0, stream>>>(x, X1, X2, W, cols, vals, rp, Y, stats);
    k_bnfin<<<1, 64, 0, stream>>>(gamma, beta, stats);
    k_pool<<<12288, 256, 0, stream>>>(Y, stats, out);
}

// Round 7
// 510.465 us; speedup vs baseline: 2.8402x; 1.3229x over previous
//
#include <hip/hip_runtime.h>
#include <hip/hip_bf16.h>

#define V     49152
#define NNZ   442368
#define EPS   1e-5f
#define VOUT  12288
#define SCW   132   // padded LDS row stride (mult of 4 for float4)

__device__ __forceinline__ unsigned short f2b(float f) {
    __hip_bfloat16 h = __float2bfloat16(f);
    return *reinterpret_cast<unsigned short*>(&h);
}
__device__ __forceinline__ float b2f(unsigned short u) {
    return __uint_as_float((unsigned)u << 16);
}

// ---------------- row_ptr via binary search + zero stats ----------------
__global__ __launch_bounds__(256) void k_rowptr(const int* __restrict__ rows,
                                                int* __restrict__ rp,
                                                float* __restrict__ stats) {
    int r = blockIdx.x * blockDim.x + threadIdx.x;
    if (r <= V) {
        int lo = 0, hi = NNZ;
        while (lo < hi) {
            int m = (lo + hi) >> 1;
            if (rows[m] < r) lo = m + 1; else hi = m;
        }
        rp[r] = lo;
    }
    if (blockIdx.x == 0 && threadIdx.x < 256) stats[threadIdx.x] = 0.f;
}

// ---------------- transpose x [B,V,32] f32 -> xbf [V, b*32+i] bf16 ----------------
__global__ __launch_bounds__(256) void k_xpose(const float* __restrict__ x,
                                               unsigned short* __restrict__ xbf) {
    int id = blockIdx.x * 256 + threadIdx.x;   // V*128 ids
    int i4 = id & 7;
    int b  = (id >> 3) & 15;
    int v  = id >> 7;
    float4 q = *(const float4*)&x[((size_t)b * V + v) * 32 + i4 * 4];
    ushort4 u = {f2b(q.x), f2b(q.y), f2b(q.z), f2b(q.w)};
    *(ushort4*)&xbf[(size_t)v * 512 + b * 32 + i4 * 4] = u;
}

// ---------------- X1 = L @ X0 : one wave per vertex, bf16 gather ----------------
__global__ __launch_bounds__(256) void k_spmm1(const unsigned short* __restrict__ xbf,
                                               const int* __restrict__ cols,
                                               const float* __restrict__ vals,
                                               const int* __restrict__ rp,
                                               unsigned short* __restrict__ X1) {
    int t = threadIdx.x;
    int wave = t >> 6, lane = t & 63;
    int v = blockIdx.x * 4 + wave;
    int f0 = lane * 8;
    int s = rp[v], e = rp[v + 1];
    float a[8] = {0.f, 0.f, 0.f, 0.f, 0.f, 0.f, 0.f, 0.f};
    for (int n = s; n < e; ++n) {
        int c = cols[n];
        float w = vals[n];
        union { unsigned short u[8]; uint4 q; } ld;
        ld.q = *(const uint4*)&xbf[(size_t)c * 512 + f0];
#pragma unroll
        for (int j = 0; j < 8; ++j) a[j] = fmaf(w, b2f(ld.u[j]), a[j]);
    }
    union { unsigned short u[8]; uint4 q; } st;
#pragma unroll
    for (int j = 0; j < 8; ++j) st.u[j] = f2b(a[j]);
    *(uint4*)&X1[(size_t)v * 512 + f0] = st.q;
}

// ---------------- X2 = 2 L @ X1 - X0 : one wave per vertex, bf16 ----------------
__global__ __launch_bounds__(256) void k_spmm2(const unsigned short* __restrict__ xbf,
                                               const int* __restrict__ cols,
                                               const float* __restrict__ vals,
                                               const int* __restrict__ rp,
                                               const unsigned short* __restrict__ X1,
                                               unsigned short* __restrict__ X2) {
    int t = threadIdx.x;
    int wave = t >> 6, lane = t & 63;
    int v = blockIdx.x * 4 + wave;
    int f0 = lane * 8;
    int s = rp[v], e = rp[v + 1];
    float a[8] = {0.f, 0.f, 0.f, 0.f, 0.f, 0.f, 0.f, 0.f};
    for (int n = s; n < e; ++n) {
        int c = cols[n];
        float w = vals[n];
        union { unsigned short u[8]; uint4 q; } ld;
        ld.q = *(const uint4*)&X1[(size_t)c * 512 + f0];
#pragma unroll
        for (int j = 0; j < 8; ++j) a[j] = fmaf(w, b2f(ld.u[j]), a[j]);
    }
    union { unsigned short u[8]; uint4 q; } x0;
    x0.q = *(const uint4*)&xbf[(size_t)v * 512 + f0];
    union { unsigned short u[8]; uint4 q; } st;
#pragma unroll
    for (int j = 0; j < 8; ++j) st.u[j] = f2b(2.f * a[j] - b2f(x0.u[j]));
    *(uint4*)&X2[(size_t)v * 512 + f0] = st.q;
}

// ---- fused: X3 = 2 L @ X2 - X1 (wave-parallel bf16 gather into LDS) + einsum + BN + bf16 y ----
// 8 vertices per block, 256 threads; gather: wave w handles vertices 2w, 2w+1.
__global__ __launch_bounds__(256) void k_cheb_out(const unsigned short* __restrict__ xbf,
                                                  const unsigned short* __restrict__ X1,
                                                  const unsigned short* __restrict__ X2,
                                                  const float* __restrict__ W,
                                                  const int* __restrict__ cols,
                                                  const float* __restrict__ vals,
                                                  const int* __restrict__ rp,
                                                  unsigned short* __restrict__ Y,
                                                  float* __restrict__ stats) {
    __shared__ float sW[2048];        // 8 KB, W_k as [i][o]
    __shared__ float sC[32 * SCW];    // 16.9 KB, cheb_k transposed: sC[i*SCW + r], r = vv*16+b
    __shared__ float lsum[64], lsq[64];

    int t = threadIdx.x;
    int v0 = blockIdx.x * 8;
    int wave = t >> 6, lane = t & 63;

    if (t < 64) { lsum[t] = 0.f; lsq[t] = 0.f; }

    int to = t & 7, tr = t >> 3;
    int r0 = tr * 4, o0 = to * 8;
    float acc[4][8];
#pragma unroll
    for (int j = 0; j < 4; ++j)
#pragma unroll
        for (int l = 0; l < 8; ++l) acc[j][l] = 0.f;

    // ---- k=3 first: wave-parallel gather of X3 rows straight into sC ----
    for (int j = t; j < 512; j += 256)
        *(float4*)&sW[j * 4] = *(const float4*)&W[3 * 2048 + j * 4];
    {
        int f0 = lane * 8;
#pragma unroll
        for (int u = 0; u < 2; ++u) {
            int vv = wave * 2 + u;
            int v = v0 + vv;
            int s = rp[v], e = rp[v + 1];
            float a[8] = {0.f, 0.f, 0.f, 0.f, 0.f, 0.f, 0.f, 0.f};
            for (int n = s; n < e; ++n) {
                int c = cols[n];
                float w = vals[n];
                union { unsigned short u8[8]; uint4 q; } ld;
                ld.q = *(const uint4*)&X2[(size_t)c * 512 + f0];
#pragma unroll
                for (int j = 0; j < 8; ++j) a[j] = fmaf(w, b2f(ld.u8[j]), a[j]);
            }
            union { unsigned short u8[8]; uint4 q; } p1;
            p1.q = *(const uint4*)&X1[(size_t)v * 512 + f0];
#pragma unroll
            for (int j = 0; j < 8; ++j) {
                int f = f0 + j;
                sC[(f & 31) * SCW + vv * 16 + (f >> 5)] = 2.f * a[j] - b2f(p1.u8[j]);
            }
        }
    }
    __syncthreads();
#pragma unroll
    for (int i = 0; i < 32; ++i) {
        float4 ca = *(const float4*)&sC[i * SCW + r0];
        float4 wa = *(const float4*)&sW[i * 64 + o0];
        float4 wb = *(const float4*)&sW[i * 64 + o0 + 4];
        float c[4] = {ca.x, ca.y, ca.z, ca.w};
        float w[8] = {wa.x, wa.y, wa.z, wa.w, wb.x, wb.y, wb.z, wb.w};
#pragma unroll
        for (int j = 0; j < 4; ++j)
#pragma unroll
            for (int l = 0; l < 8; ++l)
                acc[j][l] = fmaf(c[j], w[l], acc[j][l]);
    }

    // ---- k = 0,1,2 (bf16 staged reads) ----
    for (int k = 0; k < 3; ++k) {
        __syncthreads();
        for (int j = t; j < 512; j += 256)
            *(float4*)&sW[j * 4] = *(const float4*)&W[k * 2048 + j * 4];
        const unsigned short* src = (k == 0) ? xbf : (k == 1) ? X1 : X2;
        for (int j = t; j < 512; j += 256) {
            int r = j >> 2, q = j & 3;          // row 0..127, feature-octet 0..3
            int vv = r >> 4, b = r & 15;
            int v = v0 + vv;
            union { unsigned short u8[8]; uint4 q4; } val;
            val.q4 = *(const uint4*)&src[(size_t)v * 512 + b * 32 + q * 8];
#pragma unroll
            for (int m = 0; m < 8; ++m)
                sC[(q * 8 + m) * SCW + r] = b2f(val.u8[m]);
        }
        __syncthreads();
#pragma unroll
        for (int i = 0; i < 32; ++i) {
            float4 ca = *(const float4*)&sC[i * SCW + r0];
            float4 wa = *(const float4*)&sW[i * 64 + o0];
            float4 wb = *(const float4*)&sW[i * 64 + o0 + 4];
            float c[4] = {ca.x, ca.y, ca.z, ca.w};
            float w[8] = {wa.x, wa.y, wa.z, wa.w, wb.x, wb.y, wb.z, wb.w};
#pragma unroll
            for (int j = 0; j < 4; ++j)
#pragma unroll
                for (int l = 0; l < 8; ++l)
                    acc[j][l] = fmaf(c[j], w[l], acc[j][l]);
        }
    }

    // y write (bf16) — layout Y[v][b][o]
#pragma unroll
    for (int j = 0; j < 4; ++j) {
        int r = r0 + j;
        int vv = r >> 4, b = r & 15;
        union { unsigned short u[8]; uint4 q; } p;
#pragma unroll
        for (int l = 0; l < 8; ++l) p.u[l] = f2b(acc[j][l]);
        *(uint4*)&Y[(size_t)(v0 + vv) * 1024 + b * 64 + o0] = p.q;
    }

    // BN partial sums (exact fp32 accumulators)
#pragma unroll
    for (int l = 0; l < 8; ++l) {
        float s = 0.f, q = 0.f;
#pragma unroll
        for (int j = 0; j < 4; ++j) { float a = acc[j][l]; s += a; q = fmaf(a, a, q); }
        atomicAdd(&lsum[o0 + l], s);
        atomicAdd(&lsq[o0 + l], q);
    }
    __syncthreads();
    if (t < 64) {
        atomicAdd(&stats[t], lsum[t]);
        atomicAdd(&stats[64 + t], lsq[t]);
    }
}

// ---------------- finalize BN scale/shift ----------------
__global__ void k_bnfin(const float* __restrict__ gamma, const float* __restrict__ beta,
                        float* __restrict__ stats) {
    int o = threadIdx.x;
    if (o < 64) {
        float n = (float)(16 * V);
        float mean = stats[o] / n;
        float var = stats[64 + o] / n - mean * mean;
        float sc = gamma[o] * rsqrtf(var + EPS);
        stats[128 + o] = sc;
        stats[192 + o] = beta[o] - mean * sc;
    }
}

// ---------------- BN apply + ReLU + pool(4), bf16 y in ----------------
__global__ __launch_bounds__(256) void k_pool(const unsigned short* __restrict__ Y,
                                              const float* __restrict__ stats,
                                              float* __restrict__ out) {
    int id = blockIdx.x * blockDim.x + threadIdx.x;
    int o4 = id & 15;
    int b  = (id >> 4) & 15;
    int vp = id >> 8;
    float4 sc = *(const float4*)&stats[128 + o4 * 4];
    float4 sh = *(const float4*)&stats[192 + o4 * 4];
    float ax = 0.f, ay = 0.f, az = 0.f, aw = 0.f;
#pragma unroll
    for (int j = 0; j < 4; ++j) {
        ushort4 u = *(const ushort4*)&Y[(size_t)((vp * 4 + j) * 16 + b) * 64 + o4 * 4];
        float tx = b2f(u.x), ty = b2f(u.y), tz = b2f(u.z), tw = b2f(u.w);
        ax += fmaxf(fmaf(tx, sc.x, sh.x), 0.f);
        ay += fmaxf(fmaf(ty, sc.y, sh.y), 0.f);
        az += fmaxf(fmaf(tz, sc.z, sh.z), 0.f);
        aw += fmaxf(fmaf(tw, sc.w, sh.w), 0.f);
    }
    float4 res = {ax * 0.25f, ay * 0.25f, az * 0.25f, aw * 0.25f};
    *(float4*)&out[(size_t)((b * VOUT + vp) * 16 + o4) * 4] = res;
}

extern "C" void kernel_launch(void* const* d_in, const int* in_sizes, int n_in,
                              void* d_out, int out_size, void* d_ws, size_t ws_size,
                              hipStream_t stream) {
    const float* x     = (const float*)d_in[0];
    const float* vals  = (const float*)d_in[1];
    const float* W     = (const float*)d_in[2];
    const float* gamma = (const float*)d_in[3];
    const float* beta  = (const float*)d_in[4];
    const int*   rows  = (const int*)d_in[5];
    const int*   cols  = (const int*)d_in[6];
    float* out = (float*)d_out;

    char* ws = (char*)d_ws;
    unsigned short* xbf = (unsigned short*)ws;                   //  50,331,648 B
    unsigned short* X1  = (unsigned short*)(ws + 50331648UL);    //  50,331,648 B
    unsigned short* X2  = (unsigned short*)(ws + 100663296UL);   //  50,331,648 B
    unsigned short* Y   = (unsigned short*)(ws + 150994944UL);   // 100,663,296 B (bf16 [v][b][o])
    int*   rp    = (int*)(ws + 251658240UL);                     // 196,612 B
    float* stats = (float*)(ws + 251658240UL + 197120UL);        // 1 KB

    k_rowptr<<<193, 256, 0, stream>>>(rows, rp, stats);
    k_xpose<<<V * 128 / 256, 256, 0, stream>>>(x, xbf);
    k_spmm1<<<V / 4, 256, 0, stream>>>(xbf, cols, vals, rp, X1);
    k_spmm2<<<V / 4, 256, 0, stream>>>(xbf, cols, vals, rp, X1, X2);
    k_cheb_out<<<V / 8, 256, 0, stream>>>(xbf, X1, X2, W, cols, vals, rp, Y, stats);
    k_bnfin<<<1, 64, 0, stream>>>(gamma, beta, stats);
    k_pool<<<12288, 256, 0, stream>>>(Y, stats, out);
}